// Round 1
// baseline (854.164 us; speedup 1.0000x reference)
//
#include <hip/hip_runtime.h>

// ============================================================================
// Shunted-window attention block, MI355X / gfx950.
// Pipeline (all on `stream`, intermediates in d_ws):
//   1. cast x -> f16            (XH)
//   2. cast q_w/pw_w/proj_w -> f16
//   3. dwconv 3x3 (channel-last) XH -> DW (f16)
//   4. GEMM q:    XH @ q_w^T   -> QH (f16)
//   5. GEMM pw:   DW @ pw_w^T + b -> KVH (f16)   [KVH reuses XH buffer]
//   6. pooling + fc/single FCs + 7x7 local dwconv -> KB, VB (f16, tiny)
//   7. fused MFMA attention (softmax over 49)    -> AO (f16) [reuses DW]
//   8. GEMM proj: AO @ proj_w^T + b -> d_out (f32)
// ============================================================================

typedef _Float16 __attribute__((ext_vector_type(8))) f16x8;
typedef float __attribute__((ext_vector_type(4))) f32x4;

#define NB    16
#define NTOK  3136
#define CDIM  512
#define HWDIM 56

__device__ __forceinline__ void gll16(const void* g, void* l) {
    __builtin_amdgcn_global_load_lds((const __attribute__((address_space(1))) void*)g,
                                     (__attribute__((address_space(3))) void*)l, 16, 0, 0);
}

// ---------------------------------------------------------------------------
__global__ __launch_bounds__(256) void cast_f2h(const float* __restrict__ in,
                                                _Float16* __restrict__ out, int n8) {
    int i = blockIdx.x * 256 + threadIdx.x;
    if (i >= n8) return;
    const float4* p = (const float4*)in + (size_t)i * 2;
    float4 a = p[0], b = p[1];
    f16x8 o;
    o[0] = (_Float16)a.x; o[1] = (_Float16)a.y; o[2] = (_Float16)a.z; o[3] = (_Float16)a.w;
    o[4] = (_Float16)b.x; o[5] = (_Float16)b.y; o[6] = (_Float16)b.z; o[7] = (_Float16)b.w;
    *(f16x8*)(out + (size_t)i * 8) = o;
}

// ---------------------------------------------------------------------------
// Depthwise 3x3, zero pad, channel-last (B, 3136, 512). 4 pixels / block.
__global__ __launch_bounds__(256) void dwconv3x3(const _Float16* __restrict__ xh,
                                                 const float* __restrict__ w9,
                                                 const float* __restrict__ bias,
                                                 _Float16* __restrict__ out) {
    int p  = blockIdx.x * 4 + (threadIdx.x >> 6);
    int c0 = (threadIdx.x & 63) * 8;
    int b = p / NTOK;
    int n = p - b * NTOK;
    int h = n / HWDIM;
    int wq = n - h * HWDIM;
    float acc[8];
#pragma unroll
    for (int j = 0; j < 8; ++j) acc[j] = bias[c0 + j];
#pragma unroll
    for (int kh = 0; kh < 3; ++kh) {
        int hh = h + kh - 1;
        if ((unsigned)hh >= HWDIM) continue;
#pragma unroll
        for (int kw = 0; kw < 3; ++kw) {
            int ww = wq + kw - 1;
            if ((unsigned)ww >= HWDIM) continue;
            f16x8 v = *(const f16x8*)(xh + ((size_t)(b * NTOK + hh * HWDIM + ww) * CDIM + c0));
#pragma unroll
            for (int j = 0; j < 8; ++j) acc[j] += (float)v[j] * w9[(c0 + j) * 9 + kh * 3 + kw];
        }
    }
    f16x8 o;
#pragma unroll
    for (int j = 0; j < 8; ++j) o[j] = (_Float16)acc[j];
    *(f16x8*)(out + (size_t)p * CDIM + c0) = o;
}

// ---------------------------------------------------------------------------
// C = A @ B^T (+bias). A: (M,K) f16 row-major, B: (N,K) f16 row-major.
// 128x128 tile, BK=64, 4 waves (2x2 of 64x64), mfma_f32_16x16x32_f16.
// MODE: 0 = f16 out, 1 = f16 out + bias, 2 = f32 out + bias.
template <int MODE>
__global__ __launch_bounds__(256) void gemm_bt(const _Float16* __restrict__ A,
                                               const _Float16* __restrict__ B,
                                               const float* __restrict__ bias,
                                               _Float16* __restrict__ Ch,
                                               float* __restrict__ Cf,
                                               int M, int N, int K) {
    __shared__ _Float16 As[128 * 64];
    __shared__ _Float16 Bs[128 * 64];
    const int tid = threadIdx.x;
    const int lane = tid & 63;
    const int wave = tid >> 6;
    const size_t m0 = (size_t)blockIdx.x * 128;
    const int n0 = blockIdx.y * 128;
    const int wm = wave >> 1, wn = wave & 1;
    const int lr = lane & 15, lk = lane >> 4;
    const int srow = wave * 8 + (lane >> 3);
    const int scol = (lane & 7) * 8;
    f32x4 acc[4][4] = {};
    for (int kt = 0; kt < K; kt += 64) {
#pragma unroll
        for (int j = 0; j < 4; ++j) {
            gll16(A + ((m0 + j * 32 + srow) * K + kt + scol), &As[j * 2048 + wave * 512]);
            gll16(B + ((size_t)(n0 + j * 32 + srow) * K + kt + scol), &Bs[j * 2048 + wave * 512]);
        }
        __syncthreads();
#pragma unroll
        for (int ks = 0; ks < 2; ++ks) {
            f16x8 af[4], bf[4];
#pragma unroll
            for (int mi = 0; mi < 4; ++mi)
                af[mi] = *(const f16x8*)&As[(wm * 64 + mi * 16 + lr) * 64 + ks * 32 + lk * 8];
#pragma unroll
            for (int ni = 0; ni < 4; ++ni)
                bf[ni] = *(const f16x8*)&Bs[(wn * 64 + ni * 16 + lr) * 64 + ks * 32 + lk * 8];
#pragma unroll
            for (int mi = 0; mi < 4; ++mi)
#pragma unroll
                for (int ni = 0; ni < 4; ++ni)
                    acc[mi][ni] = __builtin_amdgcn_mfma_f32_16x16x32_f16(af[mi], bf[ni], acc[mi][ni], 0, 0, 0);
        }
        __syncthreads();
    }
#pragma unroll
    for (int mi = 0; mi < 4; ++mi)
#pragma unroll
        for (int ni = 0; ni < 4; ++ni) {
            const int col = n0 + wn * 64 + ni * 16 + lr;
            float bv = 0.f;
            if constexpr (MODE >= 1) bv = bias[col];
#pragma unroll
            for (int j = 0; j < 4; ++j) {
                const size_t row = m0 + wm * 64 + mi * 16 + lk * 4 + j;
                float v = acc[mi][ni][j] + bv;
                if constexpr (MODE == 2) Cf[row * N + col] = v;
                else Ch[row * N + col] = (_Float16)v;
            }
        }
}

// ---------------------------------------------------------------------------
// Pooling (exact reinterpreting-reshape semantics) + fc/single FCs + 7x7 local
// dwconv.  One block per (head, branch, b).  Outputs K,V: [b][br][head][49][32].
__global__ __launch_bounds__(256) void kv_small(const _Float16* __restrict__ kvh,
                                                const float* __restrict__ fc0, const float* __restrict__ fc1,
                                                const float* __restrict__ sg0, const float* __restrict__ sg1,
                                                const float* __restrict__ lw0, const float* __restrict__ lb0,
                                                const float* __restrict__ lw1, const float* __restrict__ lb1,
                                                _Float16* __restrict__ Kb, _Float16* __restrict__ Vb) {
    const int head = blockIdx.x;
    const int br = blockIdx.y;
    const int b = blockIdx.z;
    const float* fc = br ? fc1 : fc0;
    const float* sg = br ? sg1 : sg0;
    const float* lw = br ? lw1 : lw0;
    const float* lb = br ? lb1 : lb0;
    __shared__ float pooled[49 * 32];
    __shared__ float tmp[49 * 32];
    __shared__ float kvp[49 * 64];  // also reused as rowsum scratch for branch0
    const int tid = threadIdx.x;
    if (br == 0) {
        // rowsum[w][l] = sum_{s<32} kv[b, head*32+s, pix0(l,w)]
        for (int idx = tid; idx < 49 * 64; idx += 256) {
            int w = idx >> 6, l = idx & 63;
            int ly = l >> 3, lx = l & 7, pp = w / 7, qq = w % 7;
            int n = (ly * 7 + pp) * HWDIM + (lx * 7 + qq);
            const f16x8* src = (const f16x8*)(kvh + ((size_t)(b * NTOK + n) * CDIM + head * 32));
            float s = 0;
#pragma unroll
            for (int t = 0; t < 4; ++t) {
                f16x8 v = src[t];
#pragma unroll
                for (int j = 0; j < 8; ++j) s += (float)v[j];
            }
            kvp[idx] = s;
        }
        __syncthreads();
        for (int idx = tid; idx < 49 * 32; idx += 256) {
            int w = idx >> 5, sp = idx & 31;
            pooled[idx] = (kvp[(w << 6) + 2 * sp] + kvp[(w << 6) + 2 * sp + 1]) * (1.f / 64.f);
        }
    } else {
        // pooled[w][s'] = (1/16) sum_{j<16} kv[b, 256+head*32+(s'&1)*16+j, pix1(s'>>1, w)]
        for (int idx = tid; idx < 49 * 32; idx += 256) {
            int w = idx >> 5, t = idx & 31;
            int l = t >> 1, hf = t & 1;
            int ly = l >> 2, lx = l & 3, pp = w / 7, qq = w % 7;
            int n = (ly * 13 + pp * 2) * HWDIM + (lx * 13 + qq * 2);
            const f16x8* src = (const f16x8*)(kvh + ((size_t)(b * NTOK + n) * CDIM + 256 + head * 32 + hf * 16));
            float s = 0;
#pragma unroll
            for (int t2 = 0; t2 < 2; ++t2) {
                f16x8 v = src[t2];
#pragma unroll
                for (int j = 0; j < 8; ++j) s += (float)v[j];
            }
            pooled[idx] = s * (1.f / 16.f);
        }
    }
    __syncthreads();
    // tmp = pooled @ fc^T
    for (int idx = tid; idx < 49 * 32; idx += 256) {
        int w = idx >> 5, j = idx & 31;
        float s = 0;
#pragma unroll
        for (int k = 0; k < 32; ++k) s += pooled[(w << 5) + k] * fc[j * 32 + k];
        tmp[idx] = s;
    }
    __syncthreads();
    // kvp = tmp @ single^T  (49 x 64)
    for (int idx = tid; idx < 49 * 64; idx += 256) {
        int w = idx >> 6, o = idx & 63;
        float s = 0;
#pragma unroll
        for (int k = 0; k < 32; ++k) s += tmp[(w << 5) + k] * sg[o * 32 + k];
        kvp[idx] = s;
    }
    __syncthreads();
    const size_t base = (((size_t)b * 2 + br) * 8 + head) * 1568;
    for (int idx = tid; idx < 49 * 32; idx += 256) {
        int w = idx >> 5, sp = idx & 31;
        Kb[base + idx] = (_Float16)kvp[(w << 6) + sp];
        // v = v0 + dwconv3x3(v0-image 7x7) + local bias
        int pp = w / 7, qq = w % 7;
        int c = head * 32 + sp;
        float a = kvp[(w << 6) + 32 + sp] + lb[c];
#pragma unroll
        for (int kh = 0; kh < 3; ++kh) {
            int p2 = pp + kh - 1;
            if ((unsigned)p2 >= 7) continue;
#pragma unroll
            for (int kw = 0; kw < 3; ++kw) {
                int q2 = qq + kw - 1;
                if ((unsigned)q2 >= 7) continue;
                a += kvp[((p2 * 7 + q2) << 6) + 32 + sp] * lw[c * 9 + kh * 3 + kw];
            }
        }
        Vb[base + idx] = (_Float16)a;
    }
}

// ---------------------------------------------------------------------------
// Fused attention: per (b, branch, head), softmax(q.K^T/sqrt(32)) @ V.
// 4 waves/block, each wave owns 64 query rows (3136 = 49*64 row-tiles).
// K padded 49->64 rows (stride 40 halfs), V transposed (stride 72), P in
// per-wave LDS (stride 72) to bridge C-layout -> A-operand layout.
__global__ __launch_bounds__(256) void attn_fused(const _Float16* __restrict__ qh,
                                                  const _Float16* __restrict__ Kb,
                                                  const _Float16* __restrict__ Vb,
                                                  _Float16* __restrict__ outh) {
    const int b = blockIdx.y;
    const int br = blockIdx.z >> 3;
    const int head = blockIdx.z & 7;
    __shared__ _Float16 Kp[64 * 40];
    __shared__ _Float16 Vt[32 * 72];
    __shared__ _Float16 Pl[4][64 * 72];
    const int tid = threadIdx.x;
    const int lane = tid & 63, wave = tid >> 6;
    const size_t kvbase = (((size_t)b * 2 + br) * 8 + head) * 1568;
    for (int idx = tid; idx < 64 * 40; idx += 256) {
        int r = idx / 40, c = idx - r * 40;
        Kp[idx] = (r < 49 && c < 32) ? Kb[kvbase + r * 32 + c] : (_Float16)0.f;
    }
    for (int idx = tid; idx < 32 * 72; idx += 256) {
        int s = idx / 72, w = idx - s * 72;
        Vt[idx] = (w < 49) ? Vb[kvbase + w * 32 + s] : (_Float16)0.f;
    }
    __syncthreads();
    const int mtile = blockIdx.x * 4 + wave;
    if (mtile >= 49) return;
    const int n0 = mtile * 64;
    const int lr = lane & 15, lk = lane >> 4;
    f16x8 qf[4], kf[4];
    const size_t qrow0 = ((size_t)b * NTOK + n0) * CDIM + head * 64 + br * 32 + lk * 8;
#pragma unroll
    for (int mi = 0; mi < 4; ++mi)
        qf[mi] = *(const f16x8*)(qh + qrow0 + (size_t)(mi * 16 + lr) * CDIM);
#pragma unroll
    for (int ni = 0; ni < 4; ++ni)
        kf[ni] = *(const f16x8*)&Kp[(ni * 16 + lr) * 40 + lk * 8];
    f32x4 sacc[4][4] = {};
#pragma unroll
    for (int mi = 0; mi < 4; ++mi)
#pragma unroll
        for (int ni = 0; ni < 4; ++ni)
            sacc[mi][ni] = __builtin_amdgcn_mfma_f32_16x16x32_f16(qf[mi], kf[ni], sacc[mi][ni], 0, 0, 0);
    float den[4][4];
#pragma unroll
    for (int mi = 0; mi < 4; ++mi)
#pragma unroll
        for (int j = 0; j < 4; ++j) den[mi][j] = 0.f;
    const float SCALE = 0.17677669529663687f;  // 32^-0.5
#pragma unroll
    for (int mi = 0; mi < 4; ++mi)
#pragma unroll
        for (int ni = 0; ni < 4; ++ni) {
            const bool valid = (ni * 16 + lr) < 49;
#pragma unroll
            for (int j = 0; j < 4; ++j) {
                float e = valid ? __expf(sacc[mi][ni][j] * SCALE) : 0.f;
                sacc[mi][ni][j] = e;
                den[mi][j] += e;
            }
        }
#pragma unroll
    for (int mi = 0; mi < 4; ++mi)
#pragma unroll
        for (int j = 0; j < 4; ++j) {
            float d = den[mi][j];
            d += __shfl_xor(d, 1);
            d += __shfl_xor(d, 2);
            d += __shfl_xor(d, 4);
            d += __shfl_xor(d, 8);
            den[mi][j] = 1.f / d;
        }
    _Float16* P = Pl[wave];
#pragma unroll
    for (int mi = 0; mi < 4; ++mi)
#pragma unroll
        for (int ni = 0; ni < 4; ++ni)
#pragma unroll
            for (int j = 0; j < 4; ++j)
                P[(mi * 16 + lk * 4 + j) * 72 + ni * 16 + lr] =
                    (_Float16)(sacc[mi][ni][j] * den[mi][j]);
    f32x4 oacc[4][2] = {};
#pragma unroll
    for (int k0 = 0; k0 < 2; ++k0) {
        f16x8 vf0 = *(const f16x8*)&Vt[lr * 72 + k0 * 32 + lk * 8];
        f16x8 vf1 = *(const f16x8*)&Vt[(16 + lr) * 72 + k0 * 32 + lk * 8];
#pragma unroll
        for (int mi = 0; mi < 4; ++mi) {
            f16x8 pf = *(const f16x8*)&P[(mi * 16 + lr) * 72 + k0 * 32 + lk * 8];
            oacc[mi][0] = __builtin_amdgcn_mfma_f32_16x16x32_f16(pf, vf0, oacc[mi][0], 0, 0, 0);
            oacc[mi][1] = __builtin_amdgcn_mfma_f32_16x16x32_f16(pf, vf1, oacc[mi][1], 0, 0, 0);
        }
    }
    const size_t obase = ((size_t)b * NTOK + n0) * CDIM + br * 256 + head * 32;
#pragma unroll
    for (int mi = 0; mi < 4; ++mi)
#pragma unroll
        for (int ci = 0; ci < 2; ++ci)
#pragma unroll
            for (int j = 0; j < 4; ++j)
                outh[obase + (size_t)(mi * 16 + lk * 4 + j) * CDIM + ci * 16 + lr] =
                    (_Float16)oacc[mi][ci][j];
}

// ---------------------------------------------------------------------------
extern "C" void kernel_launch(void* const* d_in, const int* in_sizes, int n_in,
                              void* d_out, int out_size, void* d_ws, size_t ws_size,
                              hipStream_t stream) {
    const float* x       = (const float*)d_in[0];
    // d_in[1], d_in[2] = H, W (constants 56)
    const float* q_w     = (const float*)d_in[3];
    const float* kv_dw_w = (const float*)d_in[4];
    const float* kv_dw_b = (const float*)d_in[5];
    const float* kv_pw_w = (const float*)d_in[6];
    const float* kv_pw_b = (const float*)d_in[7];
    const float* fc_w0   = (const float*)d_in[8];
    const float* fc_w1   = (const float*)d_in[9];
    const float* sg_w0   = (const float*)d_in[10];
    const float* sg_w1   = (const float*)d_in[11];
    const float* lw0     = (const float*)d_in[12];
    const float* lb0     = (const float*)d_in[13];
    const float* lw1     = (const float*)d_in[14];
    const float* lb1     = (const float*)d_in[15];
    const float* proj_w  = (const float*)d_in[16];
    const float* proj_b  = (const float*)d_in[17];

    char* ws = (char*)d_ws;
    const size_t SZ_BIG = (size_t)50176 * 512 * 2;  // 51,380,224 B per f16 tensor
    _Float16* XH  = (_Float16*)(ws);                //  [0, 51.4MB)  x (f16)
    _Float16* KVH = XH;                             //  reuse after q-GEMM
    _Float16* DW  = (_Float16*)(ws + SZ_BIG);       //  dwconv out
    _Float16* AO  = DW;                             //  reuse after pw-GEMM
    _Float16* QH  = (_Float16*)(ws + 2 * SZ_BIG);
    _Float16* WQ  = (_Float16*)(ws + 3 * SZ_BIG);
    _Float16* WPW = WQ + 262144;
    _Float16* WPJ = WPW + 262144;
    _Float16* KB  = WPJ + 262144;
    _Float16* VB  = KB + (size_t)16 * 2 * 8 * 49 * 32;

    cast_f2h<<<dim3(12544), dim3(256), 0, stream>>>(x, XH, 25690112 / 8);
    cast_f2h<<<dim3(128), dim3(256), 0, stream>>>(q_w, WQ, 32768);
    cast_f2h<<<dim3(128), dim3(256), 0, stream>>>(kv_pw_w, WPW, 32768);
    cast_f2h<<<dim3(128), dim3(256), 0, stream>>>(proj_w, WPJ, 32768);

    dwconv3x3<<<dim3(12544), dim3(256), 0, stream>>>(XH, kv_dw_w, kv_dw_b, DW);

    gemm_bt<0><<<dim3(392, 4), dim3(256), 0, stream>>>(XH, WQ, nullptr, QH, nullptr, 50176, 512, 512);
    gemm_bt<1><<<dim3(392, 4), dim3(256), 0, stream>>>(DW, WPW, kv_pw_b, KVH, nullptr, 50176, 512, 512);

    kv_small<<<dim3(8, 2, 16), dim3(256), 0, stream>>>(KVH, fc_w0, fc_w1, sg_w0, sg_w1,
                                                       lw0, lb0, lw1, lb1, KB, VB);

    attn_fused<<<dim3(13, 16, 16), dim3(256), 0, stream>>>(QH, KB, VB, AO);

    gemm_bt<2><<<dim3(392, 4), dim3(256), 0, stream>>>(AO, WPJ, proj_b, nullptr, (float*)d_out,
                                                       50176, 512, 512);
}

// Round 2
// 506.206 us; speedup vs baseline: 1.6874x; 1.6874x over previous
//
#include <hip/hip_runtime.h>

// ============================================================================
// Shunted-window attention block, MI355X / gfx950.
// Pipeline (all on `stream`, intermediates in d_ws):
//   1. cast x -> f16            (XH)
//   2. cast q_w/pw_w/proj_w -> f16 ; transpose dw weights [512][9]->[9][512]
//   3. dwconv 3x3 (channel-last) XH -> DW (f16)   [2 pixels/thread, coalesced]
//   4. GEMM q:    XH @ q_w^T   -> QH (f16)
//   5. GEMM pw:   DW @ pw_w^T + b -> KVH (f16)   [KVH reuses XH buffer]
//   6. pooling + fc/single FCs + 7x7 local dwconv -> KB, VB (f16, tiny)
//   7. fused MFMA attention (softmax over 49)    -> AO (f16) [reuses DW]
//   8. GEMM proj: AO @ proj_w^T + b -> d_out (f32)
// ============================================================================

typedef _Float16 __attribute__((ext_vector_type(8))) f16x8;
typedef float __attribute__((ext_vector_type(4))) f32x4;

#define NB    16
#define NTOK  3136
#define CDIM  512
#define HWDIM 56

__device__ __forceinline__ void gll16(const void* g, void* l) {
    __builtin_amdgcn_global_load_lds((const __attribute__((address_space(1))) void*)g,
                                     (__attribute__((address_space(3))) void*)l, 16, 0, 0);
}

// ---------------------------------------------------------------------------
__global__ __launch_bounds__(256) void cast_f2h(const float* __restrict__ in,
                                                _Float16* __restrict__ out, int n8) {
    int i = blockIdx.x * 256 + threadIdx.x;
    if (i >= n8) return;
    const float4* p = (const float4*)in + (size_t)i * 2;
    float4 a = p[0], b = p[1];
    f16x8 o;
    o[0] = (_Float16)a.x; o[1] = (_Float16)a.y; o[2] = (_Float16)a.z; o[3] = (_Float16)a.w;
    o[4] = (_Float16)b.x; o[5] = (_Float16)b.y; o[6] = (_Float16)b.z; o[7] = (_Float16)b.w;
    *(f16x8*)(out + (size_t)i * 8) = o;
}

// ---------------------------------------------------------------------------
// Transpose dw weights [512][9] f32 -> [9][512] f32 (one-shot, tiny).
__global__ __launch_bounds__(256) void transpose_w(const float* __restrict__ w,
                                                   float* __restrict__ wt) {
    int i = blockIdx.x * 256 + threadIdx.x;
    if (i >= 512 * 9) return;
    int c = i / 9, t = i - c * 9;
    wt[t * 512 + c] = w[i];
}

// ---------------------------------------------------------------------------
// Depthwise 3x3, zero pad, channel-last (B, 3136, 512).
// Thread = 8 channels x vertical pixel PAIR (h0, h0+1); weights from the
// transposed [9][512] table via coalesced float4 loads, amortized over 2 px.
__global__ __launch_bounds__(256) void dwconv3x3(const _Float16* __restrict__ xh,
                                                 const float* __restrict__ wt,
                                                 const float* __restrict__ bias,
                                                 _Float16* __restrict__ out) {
    const int pr = blockIdx.x * 4 + (threadIdx.x >> 6);  // pair index
    const int c0 = (threadIdx.x & 63) * 8;
    const int b  = pr / (28 * HWDIM);
    const int rm = pr - b * (28 * HWDIM);
    const int hp = rm / HWDIM;
    const int w  = rm - hp * HWDIM;
    const int h0 = hp * 2;

    float wr[9][8];
#pragma unroll
    for (int t = 0; t < 9; ++t) {
        float4 a = *(const float4*)(wt + t * 512 + c0);
        float4 d = *(const float4*)(wt + t * 512 + c0 + 4);
        wr[t][0] = a.x; wr[t][1] = a.y; wr[t][2] = a.z; wr[t][3] = a.w;
        wr[t][4] = d.x; wr[t][5] = d.y; wr[t][6] = d.z; wr[t][7] = d.w;
    }
    float acc0[8], acc1[8];
    {
        float4 a = *(const float4*)(bias + c0);
        float4 d = *(const float4*)(bias + c0 + 4);
        acc0[0] = a.x; acc0[1] = a.y; acc0[2] = a.z; acc0[3] = a.w;
        acc0[4] = d.x; acc0[5] = d.y; acc0[6] = d.z; acc0[7] = d.w;
#pragma unroll
        for (int j = 0; j < 8; ++j) acc1[j] = acc0[j];
    }
#pragma unroll
    for (int rr = 0; rr < 4; ++rr) {
        const int row = h0 - 1 + rr;
        if ((unsigned)row >= HWDIM) continue;
#pragma unroll
        for (int kw = 0; kw < 3; ++kw) {
            const int ww = w + kw - 1;
            if ((unsigned)ww >= HWDIM) continue;
            f16x8 v = *(const f16x8*)(xh + ((size_t)(b * NTOK + row * HWDIM + ww) * CDIM + c0));
            if (rr < 3) {
                const int t = rr * 3 + kw;
#pragma unroll
                for (int j = 0; j < 8; ++j) acc0[j] += (float)v[j] * wr[t][j];
            }
            if (rr > 0) {
                const int t = (rr - 1) * 3 + kw;
#pragma unroll
                for (int j = 0; j < 8; ++j) acc1[j] += (float)v[j] * wr[t][j];
            }
        }
    }
    f16x8 o0, o1;
#pragma unroll
    for (int j = 0; j < 8; ++j) { o0[j] = (_Float16)acc0[j]; o1[j] = (_Float16)acc1[j]; }
    const size_t p0 = (size_t)(b * NTOK + h0 * HWDIM + w) * CDIM + c0;
    *(f16x8*)(out + p0) = o0;
    *(f16x8*)(out + p0 + (size_t)HWDIM * CDIM) = o1;
}

// ---------------------------------------------------------------------------
// C = A @ B^T (+bias). A: (M,K) f16 row-major, B: (N,K) f16 row-major.
// 128x128 tile, BK=64, 4 waves (2x2 of 64x64), mfma_f32_16x16x32_f16.
// MODE: 0 = f16 out, 1 = f16 out + bias, 2 = f32 out + bias.
template <int MODE>
__global__ __launch_bounds__(256) void gemm_bt(const _Float16* __restrict__ A,
                                               const _Float16* __restrict__ B,
                                               const float* __restrict__ bias,
                                               _Float16* __restrict__ Ch,
                                               float* __restrict__ Cf,
                                               int M, int N, int K) {
    __shared__ _Float16 As[128 * 64];
    __shared__ _Float16 Bs[128 * 64];
    const int tid = threadIdx.x;
    const int lane = tid & 63;
    const int wave = tid >> 6;
    const size_t m0 = (size_t)blockIdx.x * 128;
    const int n0 = blockIdx.y * 128;
    const int wm = wave >> 1, wn = wave & 1;
    const int lr = lane & 15, lk = lane >> 4;
    const int srow = wave * 8 + (lane >> 3);
    const int scol = (lane & 7) * 8;
    f32x4 acc[4][4] = {};
    for (int kt = 0; kt < K; kt += 64) {
#pragma unroll
        for (int j = 0; j < 4; ++j) {
            gll16(A + ((m0 + j * 32 + srow) * K + kt + scol), &As[j * 2048 + wave * 512]);
            gll16(B + ((size_t)(n0 + j * 32 + srow) * K + kt + scol), &Bs[j * 2048 + wave * 512]);
        }
        __syncthreads();
#pragma unroll
        for (int ks = 0; ks < 2; ++ks) {
            f16x8 af[4], bf[4];
#pragma unroll
            for (int mi = 0; mi < 4; ++mi)
                af[mi] = *(const f16x8*)&As[(wm * 64 + mi * 16 + lr) * 64 + ks * 32 + lk * 8];
#pragma unroll
            for (int ni = 0; ni < 4; ++ni)
                bf[ni] = *(const f16x8*)&Bs[(wn * 64 + ni * 16 + lr) * 64 + ks * 32 + lk * 8];
#pragma unroll
            for (int mi = 0; mi < 4; ++mi)
#pragma unroll
                for (int ni = 0; ni < 4; ++ni)
                    acc[mi][ni] = __builtin_amdgcn_mfma_f32_16x16x32_f16(af[mi], bf[ni], acc[mi][ni], 0, 0, 0);
        }
        __syncthreads();
    }
#pragma unroll
    for (int mi = 0; mi < 4; ++mi)
#pragma unroll
        for (int ni = 0; ni < 4; ++ni) {
            const int col = n0 + wn * 64 + ni * 16 + lr;
            float bv = 0.f;
            if constexpr (MODE >= 1) bv = bias[col];
#pragma unroll
            for (int j = 0; j < 4; ++j) {
                const size_t row = m0 + wm * 64 + mi * 16 + lk * 4 + j;
                float v = acc[mi][ni][j] + bv;
                if constexpr (MODE == 2) Cf[row * N + col] = v;
                else Ch[row * N + col] = (_Float16)v;
            }
        }
}

// ---------------------------------------------------------------------------
// Pooling (exact reinterpreting-reshape semantics) + fc/single FCs + 7x7 local
// dwconv.  One block per (head, branch, b).  Outputs K,V: [b][br][head][49][32].
__global__ __launch_bounds__(256) void kv_small(const _Float16* __restrict__ kvh,
                                                const float* __restrict__ fc0, const float* __restrict__ fc1,
                                                const float* __restrict__ sg0, const float* __restrict__ sg1,
                                                const float* __restrict__ lw0, const float* __restrict__ lb0,
                                                const float* __restrict__ lw1, const float* __restrict__ lb1,
                                                _Float16* __restrict__ Kb, _Float16* __restrict__ Vb) {
    const int head = blockIdx.x;
    const int br = blockIdx.y;
    const int b = blockIdx.z;
    const float* fc = br ? fc1 : fc0;
    const float* sg = br ? sg1 : sg0;
    const float* lw = br ? lw1 : lw0;
    const float* lb = br ? lb1 : lb0;
    __shared__ float pooled[49 * 32];
    __shared__ float tmp[49 * 32];
    __shared__ float kvp[49 * 64];  // also reused as rowsum scratch for branch0
    const int tid = threadIdx.x;
    if (br == 0) {
        // rowsum[w][l] = sum_{s<32} kv[b, head*32+s, pix0(l,w)]
        for (int idx = tid; idx < 49 * 64; idx += 256) {
            int w = idx >> 6, l = idx & 63;
            int ly = l >> 3, lx = l & 7, pp = w / 7, qq = w % 7;
            int n = (ly * 7 + pp) * HWDIM + (lx * 7 + qq);
            const f16x8* src = (const f16x8*)(kvh + ((size_t)(b * NTOK + n) * CDIM + head * 32));
            float s = 0;
#pragma unroll
            for (int t = 0; t < 4; ++t) {
                f16x8 v = src[t];
#pragma unroll
                for (int j = 0; j < 8; ++j) s += (float)v[j];
            }
            kvp[idx] = s;
        }
        __syncthreads();
        for (int idx = tid; idx < 49 * 32; idx += 256) {
            int w = idx >> 5, sp = idx & 31;
            pooled[idx] = (kvp[(w << 6) + 2 * sp] + kvp[(w << 6) + 2 * sp + 1]) * (1.f / 64.f);
        }
    } else {
        // pooled[w][s'] = (1/16) sum_{j<16} kv[b, 256+head*32+(s'&1)*16+j, pix1(s'>>1, w)]
        for (int idx = tid; idx < 49 * 32; idx += 256) {
            int w = idx >> 5, t = idx & 31;
            int l = t >> 1, hf = t & 1;
            int ly = l >> 2, lx = l & 3, pp = w / 7, qq = w % 7;
            int n = (ly * 13 + pp * 2) * HWDIM + (lx * 13 + qq * 2);
            const f16x8* src = (const f16x8*)(kvh + ((size_t)(b * NTOK + n) * CDIM + 256 + head * 32 + hf * 16));
            float s = 0;
#pragma unroll
            for (int t2 = 0; t2 < 2; ++t2) {
                f16x8 v = src[t2];
#pragma unroll
                for (int j = 0; j < 8; ++j) s += (float)v[j];
            }
            pooled[idx] = s * (1.f / 16.f);
        }
    }
    __syncthreads();
    // tmp = pooled @ fc^T
    for (int idx = tid; idx < 49 * 32; idx += 256) {
        int w = idx >> 5, j = idx & 31;
        float s = 0;
#pragma unroll
        for (int k = 0; k < 32; ++k) s += pooled[(w << 5) + k] * fc[j * 32 + k];
        tmp[idx] = s;
    }
    __syncthreads();
    // kvp = tmp @ single^T  (49 x 64)
    for (int idx = tid; idx < 49 * 64; idx += 256) {
        int w = idx >> 6, o = idx & 63;
        float s = 0;
#pragma unroll
        for (int k = 0; k < 32; ++k) s += tmp[(w << 5) + k] * sg[o * 32 + k];
        kvp[idx] = s;
    }
    __syncthreads();
    const size_t base = (((size_t)b * 2 + br) * 8 + head) * 1568;
    for (int idx = tid; idx < 49 * 32; idx += 256) {
        int w = idx >> 5, sp = idx & 31;
        Kb[base + idx] = (_Float16)kvp[(w << 6) + sp];
        // v = v0 + dwconv3x3(v0-image 7x7) + local bias
        int pp = w / 7, qq = w % 7;
        int c = head * 32 + sp;
        float a = kvp[(w << 6) + 32 + sp] + lb[c];
#pragma unroll
        for (int kh = 0; kh < 3; ++kh) {
            int p2 = pp + kh - 1;
            if ((unsigned)p2 >= 7) continue;
#pragma unroll
            for (int kw = 0; kw < 3; ++kw) {
                int q2 = qq + kw - 1;
                if ((unsigned)q2 >= 7) continue;
                a += kvp[((p2 * 7 + q2) << 6) + 32 + sp] * lw[c * 9 + kh * 3 + kw];
            }
        }
        Vb[base + idx] = (_Float16)a;
    }
}

// ---------------------------------------------------------------------------
// Fused attention: per (b, branch, head), softmax(q.K^T/sqrt(32)) @ V.
// 4 waves/block, each wave owns 64 query rows (3136 = 49*64 row-tiles).
__global__ __launch_bounds__(256) void attn_fused(const _Float16* __restrict__ qh,
                                                  const _Float16* __restrict__ Kb,
                                                  const _Float16* __restrict__ Vb,
                                                  _Float16* __restrict__ outh) {
    const int b = blockIdx.y;
    const int br = blockIdx.z >> 3;
    const int head = blockIdx.z & 7;
    __shared__ _Float16 Kp[64 * 40];
    __shared__ _Float16 Vt[32 * 72];
    __shared__ _Float16 Pl[4][64 * 72];
    const int tid = threadIdx.x;
    const int lane = tid & 63, wave = tid >> 6;
    const size_t kvbase = (((size_t)b * 2 + br) * 8 + head) * 1568;
    for (int idx = tid; idx < 64 * 40; idx += 256) {
        int r = idx / 40, c = idx - r * 40;
        Kp[idx] = (r < 49 && c < 32) ? Kb[kvbase + r * 32 + c] : (_Float16)0.f;
    }
    for (int idx = tid; idx < 32 * 72; idx += 256) {
        int s = idx / 72, w = idx - s * 72;
        Vt[idx] = (w < 49) ? Vb[kvbase + w * 32 + s] : (_Float16)0.f;
    }
    __syncthreads();
    const int mtile = blockIdx.x * 4 + wave;
    if (mtile >= 49) return;
    const int n0 = mtile * 64;
    const int lr = lane & 15, lk = lane >> 4;
    f16x8 qf[4], kf[4];
    const size_t qrow0 = ((size_t)b * NTOK + n0) * CDIM + head * 64 + br * 32 + lk * 8;
#pragma unroll
    for (int mi = 0; mi < 4; ++mi)
        qf[mi] = *(const f16x8*)(qh + qrow0 + (size_t)(mi * 16 + lr) * CDIM);
#pragma unroll
    for (int ni = 0; ni < 4; ++ni)
        kf[ni] = *(const f16x8*)&Kp[(ni * 16 + lr) * 40 + lk * 8];
    f32x4 sacc[4][4] = {};
#pragma unroll
    for (int mi = 0; mi < 4; ++mi)
#pragma unroll
        for (int ni = 0; ni < 4; ++ni)
            sacc[mi][ni] = __builtin_amdgcn_mfma_f32_16x16x32_f16(qf[mi], kf[ni], sacc[mi][ni], 0, 0, 0);
    float den[4][4];
#pragma unroll
    for (int mi = 0; mi < 4; ++mi)
#pragma unroll
        for (int j = 0; j < 4; ++j) den[mi][j] = 0.f;
    const float SCALE = 0.17677669529663687f;  // 32^-0.5
#pragma unroll
    for (int mi = 0; mi < 4; ++mi)
#pragma unroll
        for (int ni = 0; ni < 4; ++ni) {
            const bool valid = (ni * 16 + lr) < 49;
#pragma unroll
            for (int j = 0; j < 4; ++j) {
                float e = valid ? __expf(sacc[mi][ni][j] * SCALE) : 0.f;
                sacc[mi][ni][j] = e;
                den[mi][j] += e;
            }
        }
#pragma unroll
    for (int mi = 0; mi < 4; ++mi)
#pragma unroll
        for (int j = 0; j < 4; ++j) {
            float d = den[mi][j];
            d += __shfl_xor(d, 1);
            d += __shfl_xor(d, 2);
            d += __shfl_xor(d, 4);
            d += __shfl_xor(d, 8);
            den[mi][j] = 1.f / d;
        }
    _Float16* P = Pl[wave];
#pragma unroll
    for (int mi = 0; mi < 4; ++mi)
#pragma unroll
        for (int ni = 0; ni < 4; ++ni)
#pragma unroll
            for (int j = 0; j < 4; ++j)
                P[(mi * 16 + lk * 4 + j) * 72 + ni * 16 + lr] =
                    (_Float16)(sacc[mi][ni][j] * den[mi][j]);
    f32x4 oacc[4][2] = {};
#pragma unroll
    for (int k0 = 0; k0 < 2; ++k0) {
        f16x8 vf0 = *(const f16x8*)&Vt[lr * 72 + k0 * 32 + lk * 8];
        f16x8 vf1 = *(const f16x8*)&Vt[(16 + lr) * 72 + k0 * 32 + lk * 8];
#pragma unroll
        for (int mi = 0; mi < 4; ++mi) {
            f16x8 pf = *(const f16x8*)&P[(mi * 16 + lr) * 72 + k0 * 32 + lk * 8];
            oacc[mi][0] = __builtin_amdgcn_mfma_f32_16x16x32_f16(pf, vf0, oacc[mi][0], 0, 0, 0);
            oacc[mi][1] = __builtin_amdgcn_mfma_f32_16x16x32_f16(pf, vf1, oacc[mi][1], 0, 0, 0);
        }
    }
    const size_t obase = ((size_t)b * NTOK + n0) * CDIM + br * 256 + head * 32;
#pragma unroll
    for (int mi = 0; mi < 4; ++mi)
#pragma unroll
        for (int ci = 0; ci < 2; ++ci)
#pragma unroll
            for (int j = 0; j < 4; ++j)
                outh[obase + (size_t)(mi * 16 + lk * 4 + j) * CDIM + ci * 16 + lr] =
                    (_Float16)oacc[mi][ci][j];
}

// ---------------------------------------------------------------------------
extern "C" void kernel_launch(void* const* d_in, const int* in_sizes, int n_in,
                              void* d_out, int out_size, void* d_ws, size_t ws_size,
                              hipStream_t stream) {
    const float* x       = (const float*)d_in[0];
    // d_in[1], d_in[2] = H, W (constants 56)
    const float* q_w     = (const float*)d_in[3];
    const float* kv_dw_w = (const float*)d_in[4];
    const float* kv_dw_b = (const float*)d_in[5];
    const float* kv_pw_w = (const float*)d_in[6];
    const float* kv_pw_b = (const float*)d_in[7];
    const float* fc_w0   = (const float*)d_in[8];
    const float* fc_w1   = (const float*)d_in[9];
    const float* sg_w0   = (const float*)d_in[10];
    const float* sg_w1   = (const float*)d_in[11];
    const float* lw0     = (const float*)d_in[12];
    const float* lb0     = (const float*)d_in[13];
    const float* lw1     = (const float*)d_in[14];
    const float* lb1     = (const float*)d_in[15];
    const float* proj_w  = (const float*)d_in[16];
    const float* proj_b  = (const float*)d_in[17];

    char* ws = (char*)d_ws;
    const size_t SZ_BIG = (size_t)50176 * 512 * 2;  // 51,380,224 B per f16 tensor
    _Float16* XH  = (_Float16*)(ws);                //  [0, 51.4MB)  x (f16)
    _Float16* KVH = XH;                             //  reuse after q-GEMM
    _Float16* DW  = (_Float16*)(ws + SZ_BIG);       //  dwconv out
    _Float16* AO  = DW;                             //  reuse after pw-GEMM
    _Float16* QH  = (_Float16*)(ws + 2 * SZ_BIG);
    _Float16* WQ  = (_Float16*)(ws + 3 * SZ_BIG);
    _Float16* WPW = WQ + 262144;
    _Float16* WPJ = WPW + 262144;
    _Float16* KB  = WPJ + 262144;
    _Float16* VB  = KB + (size_t)16 * 2 * 8 * 49 * 32;
    float*    WT  = (float*)(VB + (size_t)16 * 2 * 8 * 49 * 32);  // 9x512 f32

    cast_f2h<<<dim3(12544), dim3(256), 0, stream>>>(x, XH, 25690112 / 8);
    cast_f2h<<<dim3(128), dim3(256), 0, stream>>>(q_w, WQ, 32768);
    cast_f2h<<<dim3(128), dim3(256), 0, stream>>>(kv_pw_w, WPW, 32768);
    cast_f2h<<<dim3(128), dim3(256), 0, stream>>>(proj_w, WPJ, 32768);
    transpose_w<<<dim3(18), dim3(256), 0, stream>>>(kv_dw_w, WT);

    dwconv3x3<<<dim3(6272), dim3(256), 0, stream>>>(XH, WT, kv_dw_b, DW);

    gemm_bt<0><<<dim3(392, 4), dim3(256), 0, stream>>>(XH, WQ, nullptr, QH, nullptr, 50176, 512, 512);
    gemm_bt<1><<<dim3(392, 4), dim3(256), 0, stream>>>(DW, WPW, kv_pw_b, KVH, nullptr, 50176, 512, 512);

    kv_small<<<dim3(8, 2, 16), dim3(256), 0, stream>>>(KVH, fc_w0, fc_w1, sg_w0, sg_w1,
                                                       lw0, lb0, lw1, lb1, KB, VB);

    attn_fused<<<dim3(13, 16, 16), dim3(256), 0, stream>>>(QH, KB, VB, AO);

    gemm_bt<2><<<dim3(392, 4), dim3(256), 0, stream>>>(AO, WPJ, proj_b, nullptr, (float*)d_out,
                                                       50176, 512, 512);
}

// Round 4
// 486.120 us; speedup vs baseline: 1.7571x; 1.0413x over previous
//
#include <hip/hip_runtime.h>

// ============================================================================
// Shunted-window attention block, MI355X / gfx950.  (Resubmission of R3 —
// previous bench died on container acquire, no kernel verdict.)
// Layout trick: Q and attn-out stored HEAD-BLOCKED: [b][slice][n][32] where
// slice = col>>5 in each tensor's natural column order; base = (b*16+slice)*100352.
// Pipeline:
//   1. cast x -> f16 (XH); prep: cast 3 weights + transpose dw weights
//   2. dwconv 3x3 (channel-last) XH -> DW (f16)
//   3. GEMM q:    XH @ q_w^T   -> Q'  (f16 head-blocked)
//   4. GEMM pw:   DW @ pw_w^T + b -> KVH (f16 row-major)  [reuses XH buffer]
//   5. pooling + fc/single FCs + local dwconv -> KB, VB (f16, tiny)
//   6. fused MFMA attention (softmax over 49) -> AO' (f16 head-blocked, reuses DW)
//   7. GEMM proj: AO' @ proj_w^T + b -> d_out (f32)   [A staged from head-blocked]
// ============================================================================

typedef _Float16 __attribute__((ext_vector_type(8))) f16x8;
typedef _Float16 __attribute__((ext_vector_type(4))) f16x4;
typedef float __attribute__((ext_vector_type(4))) f32x4;

#define NB    16
#define NTOK  3136
#define CDIM  512
#define HWDIM 56
#define SLICE 100352  // 3136*32 halfs per (b,slice) panel

__device__ __forceinline__ void gll16(const void* g, void* l) {
    __builtin_amdgcn_global_load_lds((const __attribute__((address_space(1))) void*)g,
                                     (__attribute__((address_space(3))) void*)l, 16, 0, 0);
}

// ---------------------------------------------------------------------------
__global__ __launch_bounds__(256) void cast_f2h(const float* __restrict__ in,
                                                _Float16* __restrict__ out, int n8) {
    int i = blockIdx.x * 256 + threadIdx.x;
    if (i >= n8) return;
    const float4* p = (const float4*)in + (size_t)i * 2;
    float4 a = p[0], b = p[1];
    f16x8 o;
    o[0] = (_Float16)a.x; o[1] = (_Float16)a.y; o[2] = (_Float16)a.z; o[3] = (_Float16)a.w;
    o[4] = (_Float16)b.x; o[5] = (_Float16)b.y; o[6] = (_Float16)b.z; o[7] = (_Float16)b.w;
    *(f16x8*)(out + (size_t)i * 8) = o;
}

// ---------------------------------------------------------------------------
// One-shot weight prep: cast q/pw/proj weights to f16 + transpose dw weights.
__global__ __launch_bounds__(256) void prep(const float* __restrict__ q_w,
                                            const float* __restrict__ pw_w,
                                            const float* __restrict__ pj_w,
                                            const float* __restrict__ dw_w,
                                            _Float16* __restrict__ WQ,
                                            _Float16* __restrict__ WPW,
                                            _Float16* __restrict__ WPJ,
                                            float* __restrict__ WT) {
    int bid = blockIdx.x;
    if (bid < 384) {
        const float* src = bid < 128 ? q_w : (bid < 256 ? pw_w : pj_w);
        _Float16* dst = bid < 128 ? WQ : (bid < 256 ? WPW : WPJ);
        int i = (bid & 127) * 256 + threadIdx.x;
        const float4* p = (const float4*)src + (size_t)i * 2;
        float4 a = p[0], b = p[1];
        f16x8 o;
        o[0] = (_Float16)a.x; o[1] = (_Float16)a.y; o[2] = (_Float16)a.z; o[3] = (_Float16)a.w;
        o[4] = (_Float16)b.x; o[5] = (_Float16)b.y; o[6] = (_Float16)b.z; o[7] = (_Float16)b.w;
        *(f16x8*)(dst + (size_t)i * 8) = o;
    } else {
        int i = (bid - 384) * 256 + threadIdx.x;
        if (i < 512 * 9) {
            int c = i / 9, t = i - c * 9;
            WT[t * 512 + c] = dw_w[i];
        }
    }
}

// ---------------------------------------------------------------------------
// Depthwise 3x3, zero pad, channel-last. Vertical pixel pair per thread.
__global__ __launch_bounds__(256) void dwconv3x3(const _Float16* __restrict__ xh,
                                                 const float* __restrict__ wt,
                                                 const float* __restrict__ bias,
                                                 _Float16* __restrict__ out) {
    const int pr = blockIdx.x * 4 + (threadIdx.x >> 6);  // pair index
    const int c0 = (threadIdx.x & 63) * 8;
    const int b  = pr / (28 * HWDIM);
    const int rm = pr - b * (28 * HWDIM);
    const int hp = rm / HWDIM;
    const int w  = rm - hp * HWDIM;
    const int h0 = hp * 2;

    float wr[9][8];
#pragma unroll
    for (int t = 0; t < 9; ++t) {
        float4 a = *(const float4*)(wt + t * 512 + c0);
        float4 d = *(const float4*)(wt + t * 512 + c0 + 4);
        wr[t][0] = a.x; wr[t][1] = a.y; wr[t][2] = a.z; wr[t][3] = a.w;
        wr[t][4] = d.x; wr[t][5] = d.y; wr[t][6] = d.z; wr[t][7] = d.w;
    }
    float acc0[8], acc1[8];
    {
        float4 a = *(const float4*)(bias + c0);
        float4 d = *(const float4*)(bias + c0 + 4);
        acc0[0] = a.x; acc0[1] = a.y; acc0[2] = a.z; acc0[3] = a.w;
        acc0[4] = d.x; acc0[5] = d.y; acc0[6] = d.z; acc0[7] = d.w;
#pragma unroll
        for (int j = 0; j < 8; ++j) acc1[j] = acc0[j];
    }
#pragma unroll
    for (int rr = 0; rr < 4; ++rr) {
        const int row = h0 - 1 + rr;
        if ((unsigned)row >= HWDIM) continue;
#pragma unroll
        for (int kw = 0; kw < 3; ++kw) {
            const int ww = w + kw - 1;
            if ((unsigned)ww >= HWDIM) continue;
            f16x8 v = *(const f16x8*)(xh + ((size_t)(b * NTOK + row * HWDIM + ww) * CDIM + c0));
            if (rr < 3) {
                const int t = rr * 3 + kw;
#pragma unroll
                for (int j = 0; j < 8; ++j) acc0[j] += (float)v[j] * wr[t][j];
            }
            if (rr > 0) {
                const int t = (rr - 1) * 3 + kw;
#pragma unroll
                for (int j = 0; j < 8; ++j) acc1[j] += (float)v[j] * wr[t][j];
            }
        }
    }
    f16x8 o0, o1;
#pragma unroll
    for (int j = 0; j < 8; ++j) { o0[j] = (_Float16)acc0[j]; o1[j] = (_Float16)acc1[j]; }
    const size_t p0 = (size_t)(b * NTOK + h0 * HWDIM + w) * CDIM + c0;
    *(f16x8*)(out + p0) = o0;
    *(f16x8*)(out + p0 + (size_t)HWDIM * CDIM) = o1;
}

// ---------------------------------------------------------------------------
// C = A @ B^T (+bias). 128x128 tile, BK=64, 4 waves, mfma_f32_16x16x32_f16.
// MODE 0: q-GEMM  — A row-major,      C -> f16 head-blocked Q'.
// MODE 1: pw-GEMM — A row-major,      C -> f16 row-major + bias.
// MODE 2: proj    — A head-blocked,   C -> f32 row-major + bias.
template <int MODE>
__global__ __launch_bounds__(256) void gemm_bt(const _Float16* __restrict__ A,
                                               const _Float16* __restrict__ B,
                                               const float* __restrict__ bias,
                                               _Float16* __restrict__ Ch,
                                               float* __restrict__ Cf,
                                               int M, int N, int K) {
    __shared__ _Float16 As[128 * 64];
    __shared__ _Float16 Bs[128 * 64];
    const int tid = threadIdx.x;
    const int lane = tid & 63;
    const int wave = tid >> 6;
    const size_t m0 = (size_t)blockIdx.x * 128;
    const int n0 = blockIdx.y * 128;
    const int wm = wave >> 1, wn = wave & 1;
    const int lr = lane & 15, lk = lane >> 4;
    const int srow = wave * 8 + (lane >> 3);
    const int scol = (lane & 7) * 8;

    unsigned bj[4], nj[4];
    const int shalf = scol >> 5;     // 0 or 1: which 32-col slice of the K-tile
    const int wcol = scol & 31;
    if constexpr (MODE == 2) {
#pragma unroll
        for (int j = 0; j < 4; ++j) {
            unsigned row = (unsigned)m0 + j * 32 + srow;
            bj[j] = row / 3136u;
            nj[j] = row - bj[j] * 3136u;
        }
    }

    f32x4 acc[4][4] = {};
    for (int kt = 0; kt < K; kt += 64) {
        if constexpr (MODE == 2) {
            const int s = (kt >> 5) + shalf;                      // slice 0..15
            const size_t soff = (size_t)s * SLICE + wcol;
#pragma unroll
            for (int j = 0; j < 4; ++j) {
                gll16(A + (size_t)bj[j] * 16 * SLICE + soff + (size_t)nj[j] * 32,
                      &As[j * 2048 + wave * 512]);
                gll16(B + ((size_t)(n0 + j * 32 + srow) * K + kt + scol),
                      &Bs[j * 2048 + wave * 512]);
            }
        } else {
#pragma unroll
            for (int j = 0; j < 4; ++j) {
                gll16(A + ((m0 + j * 32 + srow) * K + kt + scol), &As[j * 2048 + wave * 512]);
                gll16(B + ((size_t)(n0 + j * 32 + srow) * K + kt + scol), &Bs[j * 2048 + wave * 512]);
            }
        }
        __syncthreads();
#pragma unroll
        for (int ks = 0; ks < 2; ++ks) {
            f16x8 af[4], bf[4];
#pragma unroll
            for (int mi = 0; mi < 4; ++mi)
                af[mi] = *(const f16x8*)&As[(wm * 64 + mi * 16 + lr) * 64 + ks * 32 + lk * 8];
#pragma unroll
            for (int ni = 0; ni < 4; ++ni)
                bf[ni] = *(const f16x8*)&Bs[(wn * 64 + ni * 16 + lr) * 64 + ks * 32 + lk * 8];
#pragma unroll
            for (int mi = 0; mi < 4; ++mi)
#pragma unroll
                for (int ni = 0; ni < 4; ++ni)
                    acc[mi][ni] = __builtin_amdgcn_mfma_f32_16x16x32_f16(af[mi], bf[ni], acc[mi][ni], 0, 0, 0);
        }
        __syncthreads();
    }

    if constexpr (MODE == 0) {
        // scatter to head-blocked Q': base = (b*16 + (col>>5))*SLICE, within = col&31
#pragma unroll
        for (int mi = 0; mi < 4; ++mi)
#pragma unroll
            for (int ni = 0; ni < 4; ++ni) {
                const int col = n0 + wn * 64 + ni * 16 + lr;
                const int sl = col >> 5, sc = col & 31;
#pragma unroll
                for (int j = 0; j < 4; ++j) {
                    unsigned row = (unsigned)m0 + wm * 64 + mi * 16 + lk * 4 + j;
                    unsigned bb = row / 3136u, nn = row - bb * 3136u;
                    Ch[((size_t)bb * 16 + sl) * SLICE + (size_t)nn * 32 + sc] =
                        (_Float16)acc[mi][ni][j];
                }
            }
    } else {
#pragma unroll
        for (int mi = 0; mi < 4; ++mi)
#pragma unroll
            for (int ni = 0; ni < 4; ++ni) {
                const int col = n0 + wn * 64 + ni * 16 + lr;
                const float bv = bias[col];
#pragma unroll
                for (int j = 0; j < 4; ++j) {
                    const size_t row = m0 + wm * 64 + mi * 16 + lk * 4 + j;
                    float v = acc[mi][ni][j] + bv;
                    if constexpr (MODE == 2) Cf[row * N + col] = v;
                    else Ch[row * N + col] = (_Float16)v;
                }
            }
    }
}

// ---------------------------------------------------------------------------
// Pooling (exact reinterpreting-reshape semantics) + fc/single FCs + 7x7 local
// dwconv.  One block per (head, branch, b).  Outputs K,V: [b][br][head][49][32].
__global__ __launch_bounds__(256) void kv_small(const _Float16* __restrict__ kvh,
                                                const float* __restrict__ fc0, const float* __restrict__ fc1,
                                                const float* __restrict__ sg0, const float* __restrict__ sg1,
                                                const float* __restrict__ lw0, const float* __restrict__ lb0,
                                                const float* __restrict__ lw1, const float* __restrict__ lb1,
                                                _Float16* __restrict__ Kb, _Float16* __restrict__ Vb) {
    const int head = blockIdx.x;
    const int br = blockIdx.y;
    const int b = blockIdx.z;
    const float* fc = br ? fc1 : fc0;
    const float* sg = br ? sg1 : sg0;
    const float* lw = br ? lw1 : lw0;
    const float* lb = br ? lb1 : lb0;
    __shared__ float pooled[49 * 32];
    __shared__ float tmp[49 * 32];
    __shared__ float kvp[49 * 64];
    const int tid = threadIdx.x;
    if (br == 0) {
        for (int idx = tid; idx < 49 * 64; idx += 256) {
            int w = idx >> 6, l = idx & 63;
            int ly = l >> 3, lx = l & 7, pp = w / 7, qq = w % 7;
            int n = (ly * 7 + pp) * HWDIM + (lx * 7 + qq);
            const f16x8* src = (const f16x8*)(kvh + ((size_t)(b * NTOK + n) * CDIM + head * 32));
            float s = 0;
#pragma unroll
            for (int t = 0; t < 4; ++t) {
                f16x8 v = src[t];
#pragma unroll
                for (int j = 0; j < 8; ++j) s += (float)v[j];
            }
            kvp[idx] = s;
        }
        __syncthreads();
        for (int idx = tid; idx < 49 * 32; idx += 256) {
            int w = idx >> 5, sp = idx & 31;
            pooled[idx] = (kvp[(w << 6) + 2 * sp] + kvp[(w << 6) + 2 * sp + 1]) * (1.f / 64.f);
        }
    } else {
        for (int idx = tid; idx < 49 * 32; idx += 256) {
            int w = idx >> 5, t = idx & 31;
            int l = t >> 1, hf = t & 1;
            int ly = l >> 2, lx = l & 3, pp = w / 7, qq = w % 7;
            int n = (ly * 13 + pp * 2) * HWDIM + (lx * 13 + qq * 2);
            const f16x8* src = (const f16x8*)(kvh + ((size_t)(b * NTOK + n) * CDIM + 256 + head * 32 + hf * 16));
            float s = 0;
#pragma unroll
            for (int t2 = 0; t2 < 2; ++t2) {
                f16x8 v = src[t2];
#pragma unroll
                for (int j = 0; j < 8; ++j) s += (float)v[j];
            }
            pooled[idx] = s * (1.f / 16.f);
        }
    }
    __syncthreads();
    for (int idx = tid; idx < 49 * 32; idx += 256) {
        int w = idx >> 5, j = idx & 31;
        float s = 0;
#pragma unroll
        for (int k = 0; k < 32; ++k) s += pooled[(w << 5) + k] * fc[j * 32 + k];
        tmp[idx] = s;
    }
    __syncthreads();
    for (int idx = tid; idx < 49 * 64; idx += 256) {
        int w = idx >> 6, o = idx & 63;
        float s = 0;
#pragma unroll
        for (int k = 0; k < 32; ++k) s += tmp[(w << 5) + k] * sg[o * 32 + k];
        kvp[idx] = s;
    }
    __syncthreads();
    const size_t base = (((size_t)b * 2 + br) * 8 + head) * 1568;
    for (int idx = tid; idx < 49 * 32; idx += 256) {
        int w = idx >> 5, sp = idx & 31;
        Kb[base + idx] = (_Float16)kvp[(w << 6) + sp];
        int pp = w / 7, qq = w % 7;
        int c = head * 32 + sp;
        float a = kvp[(w << 6) + 32 + sp] + lb[c];
#pragma unroll
        for (int kh = 0; kh < 3; ++kh) {
            int p2 = pp + kh - 1;
            if ((unsigned)p2 >= 7) continue;
#pragma unroll
            for (int kw = 0; kw < 3; ++kw) {
                int q2 = qq + kw - 1;
                if ((unsigned)q2 >= 7) continue;
                a += kvp[((p2 * 7 + q2) << 6) + 32 + sp] * lw[c * 9 + kh * 3 + kw];
            }
        }
        Vb[base + idx] = (_Float16)a;
    }
}

// ---------------------------------------------------------------------------
// Fused attention v2: coalesced head-blocked Q loads, two-half P buffer,
// LDS-restaged coalesced output. Per (b,br,head); wave = one 64-row q-tile.
__global__ __launch_bounds__(256) void attn_fused(const _Float16* __restrict__ Qp,
                                                  const _Float16* __restrict__ Kb,
                                                  const _Float16* __restrict__ Vb,
                                                  _Float16* __restrict__ AOp) {
    const int b = blockIdx.y;
    const int br = blockIdx.z >> 3;
    const int head = blockIdx.z & 7;
    __shared__ _Float16 Kp[64 * 40];       // rows=kv slot (pad->64), cols=s(32), stride 40
    __shared__ _Float16 Vt[32 * 72];       // rows=s(32), cols=kv slot (pad->64), stride 72
    __shared__ _Float16 Pw[4][32 * 72];    // per-wave P half (32 q-rows x 64 kv), stride 72
    const int tid = threadIdx.x;
    const int lane = tid & 63, wave = tid >> 6;
    const size_t kvbase = (((size_t)b * 2 + br) * 8 + head) * 1568;
    {   // K stage: 64 rows x 4 chunks of 8 halfs
        int r = tid >> 2, ck = tid & 3;
        f16x8 v = {};
        if (r < 49) v = *(const f16x8*)(Kb + kvbase + r * 32 + ck * 8);
        *(f16x8*)&Kp[r * 40 + ck * 8] = v;
    }
    for (int idx = tid; idx < 64 * 32; idx += 256) {   // V stage transposed
        int w = idx >> 5, s = idx & 31;
        Vt[s * 72 + w] = (w < 49) ? Vb[kvbase + w * 32 + s] : (_Float16)0.f;
    }
    __syncthreads();
    const int mtile = blockIdx.x * 4 + wave;
    if (mtile >= 49) return;
    const int n0 = mtile * 64;
    const int lr = lane & 15, lk = lane >> 4;
    // Q' slice = head*2+br ; AO' slice = br*8+head (each tensor's natural order)
    const size_t qsl = ((size_t)b * 16 + head * 2 + br) * SLICE + (size_t)n0 * 32;
    const size_t osl = ((size_t)b * 16 + br * 8 + head) * SLICE + (size_t)n0 * 32;

    f16x8 qf[4], kf[4];
#pragma unroll
    for (int mi = 0; mi < 4; ++mi)
        qf[mi] = *(const f16x8*)(Qp + qsl + (size_t)(mi * 16 + lr) * 32 + lk * 8);
#pragma unroll
    for (int ni = 0; ni < 4; ++ni)
        kf[ni] = *(const f16x8*)&Kp[(ni * 16 + lr) * 40 + lk * 8];
    f32x4 sacc[4][4] = {};
#pragma unroll
    for (int mi = 0; mi < 4; ++mi)
#pragma unroll
        for (int ni = 0; ni < 4; ++ni)
            sacc[mi][ni] = __builtin_amdgcn_mfma_f32_16x16x32_f16(qf[mi], kf[ni], sacc[mi][ni], 0, 0, 0);

    float den[4][4];
#pragma unroll
    for (int mi = 0; mi < 4; ++mi)
#pragma unroll
        for (int j = 0; j < 4; ++j) den[mi][j] = 0.f;
    const float SCALE = 0.17677669529663687f;  // 32^-0.5
#pragma unroll
    for (int mi = 0; mi < 4; ++mi)
#pragma unroll
        for (int ni = 0; ni < 4; ++ni) {
            const bool valid = (ni * 16 + lr) < 49;
#pragma unroll
            for (int j = 0; j < 4; ++j) {
                float e = valid ? __expf(sacc[mi][ni][j] * SCALE) : 0.f;
                sacc[mi][ni][j] = e;
                den[mi][j] += e;
            }
        }
#pragma unroll
    for (int mi = 0; mi < 4; ++mi)
#pragma unroll
        for (int j = 0; j < 4; ++j) {
            float d = den[mi][j];
            d += __shfl_xor(d, 1);
            d += __shfl_xor(d, 2);
            d += __shfl_xor(d, 4);
            d += __shfl_xor(d, 8);
            den[mi][j] = 1.f / d;
        }
    // pack P to f16 early (frees sacc registers)
    f16x4 ph[4][4];
#pragma unroll
    for (int mi = 0; mi < 4; ++mi)
#pragma unroll
        for (int ni = 0; ni < 4; ++ni)
#pragma unroll
            for (int j = 0; j < 4; ++j)
                ph[mi][ni][j] = (_Float16)(sacc[mi][ni][j] * den[mi][j]);

    _Float16* P = Pw[wave];
#pragma unroll
    for (int h = 0; h < 2; ++h) {
        // write P half: q-rows h*32..h*32+31
#pragma unroll
        for (int mh = 0; mh < 2; ++mh) {
            const int mi = h * 2 + mh;
#pragma unroll
            for (int ni = 0; ni < 4; ++ni)
#pragma unroll
                for (int j = 0; j < 4; ++j)
                    P[(mh * 16 + lk * 4 + j) * 72 + ni * 16 + lr] = ph[mi][ni][j];
        }
        f32x4 oacc[2][2] = {};
#pragma unroll
        for (int k0 = 0; k0 < 2; ++k0) {
            f16x8 vf0 = *(const f16x8*)&Vt[lr * 72 + k0 * 32 + lk * 8];
            f16x8 vf1 = *(const f16x8*)&Vt[(16 + lr) * 72 + k0 * 32 + lk * 8];
#pragma unroll
            for (int mh = 0; mh < 2; ++mh) {
                f16x8 pf = *(const f16x8*)&P[(mh * 16 + lr) * 72 + k0 * 32 + lk * 8];
                oacc[mh][0] = __builtin_amdgcn_mfma_f32_16x16x32_f16(pf, vf0, oacc[mh][0], 0, 0, 0);
                oacc[mh][1] = __builtin_amdgcn_mfma_f32_16x16x32_f16(pf, vf1, oacc[mh][1], 0, 0, 0);
            }
        }
        // restage out half into P region (stride 40), then 2 coalesced 1KB stores
#pragma unroll
        for (int mh = 0; mh < 2; ++mh)
#pragma unroll
            for (int ci = 0; ci < 2; ++ci)
#pragma unroll
                for (int j = 0; j < 4; ++j)
                    P[(mh * 16 + lk * 4 + j) * 40 + ci * 16 + lr] = (_Float16)(oacc[mh][ci][j]);
#pragma unroll
        for (int t = 0; t < 2; ++t) {
            const int idx = t * 64 + lane;
            const int row = idx >> 2, ck = idx & 3;
            f16x8 ov = *(const f16x8*)&P[row * 40 + ck * 8];
            *(f16x8*)(AOp + osl + (size_t)(h * 32 + row) * 32 + ck * 8) = ov;
        }
    }
}

// ---------------------------------------------------------------------------
extern "C" void kernel_launch(void* const* d_in, const int* in_sizes, int n_in,
                              void* d_out, int out_size, void* d_ws, size_t ws_size,
                              hipStream_t stream) {
    const float* x       = (const float*)d_in[0];
    const float* q_w     = (const float*)d_in[3];
    const float* kv_dw_w = (const float*)d_in[4];
    const float* kv_dw_b = (const float*)d_in[5];
    const float* kv_pw_w = (const float*)d_in[6];
    const float* kv_pw_b = (const float*)d_in[7];
    const float* fc_w0   = (const float*)d_in[8];
    const float* fc_w1   = (const float*)d_in[9];
    const float* sg_w0   = (const float*)d_in[10];
    const float* sg_w1   = (const float*)d_in[11];
    const float* lw0     = (const float*)d_in[12];
    const float* lb0     = (const float*)d_in[13];
    const float* lw1     = (const float*)d_in[14];
    const float* lb1     = (const float*)d_in[15];
    const float* proj_w  = (const float*)d_in[16];
    const float* proj_b  = (const float*)d_in[17];

    char* ws = (char*)d_ws;
    const size_t SZ_BIG = (size_t)50176 * 512 * 2;
    _Float16* XH  = (_Float16*)(ws);                // x f16 -> later KVH
    _Float16* KVH = XH;
    _Float16* DW  = (_Float16*)(ws + SZ_BIG);       // dwconv out -> later AO'
    _Float16* AO  = DW;
    _Float16* QH  = (_Float16*)(ws + 2 * SZ_BIG);   // Q' head-blocked
    _Float16* WQ  = (_Float16*)(ws + 3 * SZ_BIG);
    _Float16* WPW = WQ + 262144;
    _Float16* WPJ = WPW + 262144;
    _Float16* KB  = WPJ + 262144;
    _Float16* VB  = KB + (size_t)16 * 2 * 8 * 49 * 32;
    float*    WT  = (float*)(VB + (size_t)16 * 2 * 8 * 49 * 32);  // 9x512 f32

    cast_f2h<<<dim3(12544), dim3(256), 0, stream>>>(x, XH, 25690112 / 8);
    prep<<<dim3(402), dim3(256), 0, stream>>>(q_w, kv_pw_w, proj_w, kv_dw_w, WQ, WPW, WPJ, WT);

    dwconv3x3<<<dim3(6272), dim3(256), 0, stream>>>(XH, WT, kv_dw_b, DW);

    gemm_bt<0><<<dim3(392, 4), dim3(256), 0, stream>>>(XH, WQ, nullptr, QH, nullptr, 50176, 512, 512);
    gemm_bt<1><<<dim3(392, 4), dim3(256), 0, stream>>>(DW, WPW, kv_pw_b, KVH, nullptr, 50176, 512, 512);

    kv_small<<<dim3(8, 2, 16), dim3(256), 0, stream>>>(KVH, fc_w0, fc_w1, sg_w0, sg_w1,
                                                       lw0, lb0, lw1, lb1, KB, VB);

    attn_fused<<<dim3(13, 16, 16), dim3(256), 0, stream>>>(QH, KB, VB, AO);

    gemm_bt<2><<<dim3(392, 4), dim3(256), 0, stream>>>(AO, WPJ, proj_b, nullptr, (float*)d_out,
                                                       50176, 512, 512);
}

// Round 5
// 474.164 us; speedup vs baseline: 1.8014x; 1.0252x over previous
//
#include <hip/hip_runtime.h>

// ============================================================================
// Shunted-window attention block, MI355X / gfx950.
// Layout trick: Q and attn-out stored HEAD-BLOCKED: [b][slice][n][32] where
// slice = col>>5 in each tensor's natural column order; base = (b*16+slice)*100352.
// GEMMs: 128x128 tile, BK=32 double-buffered pipeline, counted vmcnt(4),
// T2-swizzled LDS (pre-swizzled gll16 source + swizzled ds_read), setprio.
// ============================================================================

typedef _Float16 __attribute__((ext_vector_type(8))) f16x8;
typedef _Float16 __attribute__((ext_vector_type(4))) f16x4;
typedef float __attribute__((ext_vector_type(4))) f32x4;

#define NB    16
#define NTOK  3136
#define CDIM  512
#define HWDIM 56
#define SLICE 100352  // 3136*32 halfs per (b,slice) panel

__device__ __forceinline__ void gll16(const void* g, void* l) {
    __builtin_amdgcn_global_load_lds((const __attribute__((address_space(1))) void*)g,
                                     (__attribute__((address_space(3))) void*)l, 16, 0, 0);
}

// ---------------------------------------------------------------------------
__global__ __launch_bounds__(256) void cast_f2h(const float* __restrict__ in,
                                                _Float16* __restrict__ out, int n8) {
    int i = blockIdx.x * 256 + threadIdx.x;
    if (i >= n8) return;
    const float4* p = (const float4*)in + (size_t)i * 2;
    float4 a = p[0], b = p[1];
    f16x8 o;
    o[0] = (_Float16)a.x; o[1] = (_Float16)a.y; o[2] = (_Float16)a.z; o[3] = (_Float16)a.w;
    o[4] = (_Float16)b.x; o[5] = (_Float16)b.y; o[6] = (_Float16)b.z; o[7] = (_Float16)b.w;
    *(f16x8*)(out + (size_t)i * 8) = o;
}

// ---------------------------------------------------------------------------
// One-shot weight prep: cast q/pw/proj weights to f16 + transpose dw weights.
__global__ __launch_bounds__(256) void prep(const float* __restrict__ q_w,
                                            const float* __restrict__ pw_w,
                                            const float* __restrict__ pj_w,
                                            const float* __restrict__ dw_w,
                                            _Float16* __restrict__ WQ,
                                            _Float16* __restrict__ WPW,
                                            _Float16* __restrict__ WPJ,
                                            float* __restrict__ WT) {
    int bid = blockIdx.x;
    if (bid < 384) {
        const float* src = bid < 128 ? q_w : (bid < 256 ? pw_w : pj_w);
        _Float16* dst = bid < 128 ? WQ : (bid < 256 ? WPW : WPJ);
        int i = (bid & 127) * 256 + threadIdx.x;
        const float4* p = (const float4*)src + (size_t)i * 2;
        float4 a = p[0], b = p[1];
        f16x8 o;
        o[0] = (_Float16)a.x; o[1] = (_Float16)a.y; o[2] = (_Float16)a.z; o[3] = (_Float16)a.w;
        o[4] = (_Float16)b.x; o[5] = (_Float16)b.y; o[6] = (_Float16)b.z; o[7] = (_Float16)b.w;
        *(f16x8*)(dst + (size_t)i * 8) = o;
    } else {
        int i = (bid - 384) * 256 + threadIdx.x;
        if (i < 512 * 9) {
            int c = i / 9, t = i - c * 9;
            WT[t * 512 + c] = dw_w[i];
        }
    }
}

// ---------------------------------------------------------------------------
// Depthwise 3x3, zero pad, channel-last. Vertical pixel pair per thread.
__global__ __launch_bounds__(256) void dwconv3x3(const _Float16* __restrict__ xh,
                                                 const float* __restrict__ wt,
                                                 const float* __restrict__ bias,
                                                 _Float16* __restrict__ out) {
    const int pr = blockIdx.x * 4 + (threadIdx.x >> 6);  // pair index
    const int c0 = (threadIdx.x & 63) * 8;
    const int b  = pr / (28 * HWDIM);
    const int rm = pr - b * (28 * HWDIM);
    const int hp = rm / HWDIM;
    const int w  = rm - hp * HWDIM;
    const int h0 = hp * 2;

    float wr[9][8];
#pragma unroll
    for (int t = 0; t < 9; ++t) {
        float4 a = *(const float4*)(wt + t * 512 + c0);
        float4 d = *(const float4*)(wt + t * 512 + c0 + 4);
        wr[t][0] = a.x; wr[t][1] = a.y; wr[t][2] = a.z; wr[t][3] = a.w;
        wr[t][4] = d.x; wr[t][5] = d.y; wr[t][6] = d.z; wr[t][7] = d.w;
    }
    float acc0[8], acc1[8];
    {
        float4 a = *(const float4*)(bias + c0);
        float4 d = *(const float4*)(bias + c0 + 4);
        acc0[0] = a.x; acc0[1] = a.y; acc0[2] = a.z; acc0[3] = a.w;
        acc0[4] = d.x; acc0[5] = d.y; acc0[6] = d.z; acc0[7] = d.w;
#pragma unroll
        for (int j = 0; j < 8; ++j) acc1[j] = acc0[j];
    }
#pragma unroll
    for (int rr = 0; rr < 4; ++rr) {
        const int row = h0 - 1 + rr;
        if ((unsigned)row >= HWDIM) continue;
#pragma unroll
        for (int kw = 0; kw < 3; ++kw) {
            const int ww = w + kw - 1;
            if ((unsigned)ww >= HWDIM) continue;
            f16x8 v = *(const f16x8*)(xh + ((size_t)(b * NTOK + row * HWDIM + ww) * CDIM + c0));
            if (rr < 3) {
                const int t = rr * 3 + kw;
#pragma unroll
                for (int j = 0; j < 8; ++j) acc0[j] += (float)v[j] * wr[t][j];
            }
            if (rr > 0) {
                const int t = (rr - 1) * 3 + kw;
#pragma unroll
                for (int j = 0; j < 8; ++j) acc1[j] += (float)v[j] * wr[t][j];
            }
        }
    }
    f16x8 o0, o1;
#pragma unroll
    for (int j = 0; j < 8; ++j) { o0[j] = (_Float16)acc0[j]; o1[j] = (_Float16)acc1[j]; }
    const size_t p0 = (size_t)(b * NTOK + h0 * HWDIM + w) * CDIM + c0;
    *(f16x8*)(out + p0) = o0;
    *(f16x8*)(out + p0 + (size_t)HWDIM * CDIM) = o1;
}

// ---------------------------------------------------------------------------
// C = A @ B^T (+bias). A: (M,K) f16, B: (N,K) f16. 128x128 tile, 4 waves.
// BK=32 double-buffered gll16 pipeline with counted vmcnt(4); T2 XOR-swizzle
// (source chunk c ^= (row>>1)&3, same on read) -> conflict-free ds_read_b128.
// Grid: (N/128, M/128)  -- n fast so A-panel-sharing blocks are adjacent.
// MODE 0: q-GEMM  A row-major,    C -> f16 head-blocked Q'.
// MODE 1: pw-GEMM A row-major,    C -> f16 row-major + bias.
// MODE 2: proj    A head-blocked, C -> f32 row-major + bias.
template <int MODE>
__global__ __launch_bounds__(256) void gemm_bt(const _Float16* __restrict__ A,
                                               const _Float16* __restrict__ B,
                                               const float* __restrict__ bias,
                                               _Float16* __restrict__ Ch,
                                               float* __restrict__ Cf,
                                               int M, int N, int K) {
    __shared__ __align__(16) _Float16 As[2][128 * 32];
    __shared__ __align__(16) _Float16 Bs[2][128 * 32];
    const int tid  = threadIdx.x;
    const int lane = tid & 63;
    const int wave = tid >> 6;
    const size_t m0 = (size_t)blockIdx.y * 128;
    const int    n0 = blockIdx.x * 128;
    const int wm = wave >> 1, wn = wave & 1;
    const int lr = lane & 15, lk = lane >> 4;
    // stage: thread covers rows row_j = j*64 + wave*16 + (lane>>2), chunk lane&3
    const int srow0 = wave * 16 + (lane >> 2);
    const int csw = ((lane & 3) ^ ((lane >> 3) & 3)) * 8;  // pre-swizzled src col (halfs)
    const int kc  = (lk ^ ((lr >> 1) & 3)) * 8;            // swizzled read col (halfs)
    const int NK = K >> 5;
    const int ldst = wave * 512;  // halfs; + j*2048

    size_t abase[2], bbase[2];
#pragma unroll
    for (int j = 0; j < 2; ++j) {
        const int row = j * 64 + srow0;
        if constexpr (MODE == 2) {
            unsigned g = (unsigned)m0 + row;
            unsigned bb = g / 3136u, nn = g - bb * 3136u;
            abase[j] = ((size_t)bb * 16) * SLICE + (size_t)nn * 32 + csw;  // + t*SLICE
        } else {
            abase[j] = (m0 + row) * (size_t)K + csw;                       // + t*32
        }
        bbase[j] = (size_t)(n0 + row) * K + csw;                           // + t*32
    }

    auto STAGE = [&](int t, int p) {
#pragma unroll
        for (int j = 0; j < 2; ++j) {
            if constexpr (MODE == 2)
                gll16(A + abase[j] + (size_t)t * SLICE, &As[p][j * 2048 + ldst]);
            else
                gll16(A + abase[j] + t * 32, &As[p][j * 2048 + ldst]);
            gll16(B + bbase[j] + t * 32, &Bs[p][j * 2048 + ldst]);
        }
    };

    f32x4 acc[4][4] = {};
    STAGE(0, 0);
    STAGE(1, 1);
    for (int kt = 0; kt < NK; ++kt) {
        const int p = kt & 1;
        if (kt == NK - 1) asm volatile("s_waitcnt vmcnt(0)" ::: "memory");
        else              asm volatile("s_waitcnt vmcnt(4)" ::: "memory");
        __builtin_amdgcn_s_barrier();
        __builtin_amdgcn_sched_barrier(0);
        f16x8 af[4], bf[4];
#pragma unroll
        for (int mi = 0; mi < 4; ++mi)
            af[mi] = *(const f16x8*)&As[p][(wm * 64 + mi * 16 + lr) * 32 + kc];
#pragma unroll
        for (int ni = 0; ni < 4; ++ni)
            bf[ni] = *(const f16x8*)&Bs[p][(wn * 64 + ni * 16 + lr) * 32 + kc];
        __builtin_amdgcn_s_setprio(1);
#pragma unroll
        for (int mi = 0; mi < 4; ++mi)
#pragma unroll
            for (int ni = 0; ni < 4; ++ni)
                acc[mi][ni] = __builtin_amdgcn_mfma_f32_16x16x32_f16(af[mi], bf[ni], acc[mi][ni], 0, 0, 0);
        __builtin_amdgcn_s_setprio(0);
        __builtin_amdgcn_sched_barrier(0);
        __builtin_amdgcn_s_barrier();
        if (kt < NK - 2) STAGE(kt + 2, p);
    }

    if constexpr (MODE == 0) {
        // scatter to head-blocked Q': base = (b*16 + (col>>5))*SLICE, within = col&31
#pragma unroll
        for (int mi = 0; mi < 4; ++mi)
#pragma unroll
            for (int ni = 0; ni < 4; ++ni) {
                const int col = n0 + wn * 64 + ni * 16 + lr;
                const int sl = col >> 5, sc = col & 31;
#pragma unroll
                for (int j = 0; j < 4; ++j) {
                    unsigned row = (unsigned)m0 + wm * 64 + mi * 16 + lk * 4 + j;
                    unsigned bb = row / 3136u, nn = row - bb * 3136u;
                    Ch[((size_t)bb * 16 + sl) * SLICE + (size_t)nn * 32 + sc] =
                        (_Float16)acc[mi][ni][j];
                }
            }
    } else {
#pragma unroll
        for (int mi = 0; mi < 4; ++mi)
#pragma unroll
            for (int ni = 0; ni < 4; ++ni) {
                const int col = n0 + wn * 64 + ni * 16 + lr;
                const float bv = bias[col];
#pragma unroll
                for (int j = 0; j < 4; ++j) {
                    const size_t row = m0 + wm * 64 + mi * 16 + lk * 4 + j;
                    float v = acc[mi][ni][j] + bv;
                    if constexpr (MODE == 2) Cf[row * N + col] = v;
                    else Ch[row * N + col] = (_Float16)v;
                }
            }
    }
}

// ---------------------------------------------------------------------------
// Pooling (exact reinterpreting-reshape semantics) + fc/single FCs + 7x7 local
// dwconv.  One block per (head, branch, b).  Outputs K,V: [b][br][head][49][32].
__global__ __launch_bounds__(256) void kv_small(const _Float16* __restrict__ kvh,
                                                const float* __restrict__ fc0, const float* __restrict__ fc1,
                                                const float* __restrict__ sg0, const float* __restrict__ sg1,
                                                const float* __restrict__ lw0, const float* __restrict__ lb0,
                                                const float* __restrict__ lw1, const float* __restrict__ lb1,
                                                _Float16* __restrict__ Kb, _Float16* __restrict__ Vb) {
    const int head = blockIdx.x;
    const int br = blockIdx.y;
    const int b = blockIdx.z;
    const float* fc = br ? fc1 : fc0;
    const float* sg = br ? sg1 : sg0;
    const float* lw = br ? lw1 : lw0;
    const float* lb = br ? lb1 : lb0;
    __shared__ float pooled[49 * 32];
    __shared__ float tmp[49 * 32];
    __shared__ float kvp[49 * 64];
    const int tid = threadIdx.x;
    if (br == 0) {
        for (int idx = tid; idx < 49 * 64; idx += 256) {
            int w = idx >> 6, l = idx & 63;
            int ly = l >> 3, lx = l & 7, pp = w / 7, qq = w % 7;
            int n = (ly * 7 + pp) * HWDIM + (lx * 7 + qq);
            const f16x8* src = (const f16x8*)(kvh + ((size_t)(b * NTOK + n) * CDIM + head * 32));
            float s = 0;
#pragma unroll
            for (int t = 0; t < 4; ++t) {
                f16x8 v = src[t];
#pragma unroll
                for (int j = 0; j < 8; ++j) s += (float)v[j];
            }
            kvp[idx] = s;
        }
        __syncthreads();
        for (int idx = tid; idx < 49 * 32; idx += 256) {
            int w = idx >> 5, sp = idx & 31;
            pooled[idx] = (kvp[(w << 6) + 2 * sp] + kvp[(w << 6) + 2 * sp + 1]) * (1.f / 64.f);
        }
    } else {
        for (int idx = tid; idx < 49 * 32; idx += 256) {
            int w = idx >> 5, t = idx & 31;
            int l = t >> 1, hf = t & 1;
            int ly = l >> 2, lx = l & 3, pp = w / 7, qq = w % 7;
            int n = (ly * 13 + pp * 2) * HWDIM + (lx * 13 + qq * 2);
            const f16x8* src = (const f16x8*)(kvh + ((size_t)(b * NTOK + n) * CDIM + 256 + head * 32 + hf * 16));
            float s = 0;
#pragma unroll
            for (int t2 = 0; t2 < 2; ++t2) {
                f16x8 v = src[t2];
#pragma unroll
                for (int j = 0; j < 8; ++j) s += (float)v[j];
            }
            pooled[idx] = s * (1.f / 16.f);
        }
    }
    __syncthreads();
    for (int idx = tid; idx < 49 * 32; idx += 256) {
        int w = idx >> 5, j = idx & 31;
        float s = 0;
#pragma unroll
        for (int k = 0; k < 32; ++k) s += pooled[(w << 5) + k] * fc[j * 32 + k];
        tmp[idx] = s;
    }
    __syncthreads();
    for (int idx = tid; idx < 49 * 64; idx += 256) {
        int w = idx >> 6, o = idx & 63;
        float s = 0;
#pragma unroll
        for (int k = 0; k < 32; ++k) s += tmp[(w << 5) + k] * sg[o * 32 + k];
        kvp[idx] = s;
    }
    __syncthreads();
    const size_t base = (((size_t)b * 2 + br) * 8 + head) * 1568;
    for (int idx = tid; idx < 49 * 32; idx += 256) {
        int w = idx >> 5, sp = idx & 31;
        Kb[base + idx] = (_Float16)kvp[(w << 6) + sp];
        int pp = w / 7, qq = w % 7;
        int c = head * 32 + sp;
        float a = kvp[(w << 6) + 32 + sp] + lb[c];
#pragma unroll
        for (int kh = 0; kh < 3; ++kh) {
            int p2 = pp + kh - 1;
            if ((unsigned)p2 >= 7) continue;
#pragma unroll
            for (int kw = 0; kw < 3; ++kw) {
                int q2 = qq + kw - 1;
                if ((unsigned)q2 >= 7) continue;
                a += kvp[((p2 * 7 + q2) << 6) + 32 + sp] * lw[c * 9 + kh * 3 + kw];
            }
        }
        Vb[base + idx] = (_Float16)a;
    }
}

// ---------------------------------------------------------------------------
// Fused attention v2: coalesced head-blocked Q loads, two-half P buffer,
// LDS-restaged coalesced output. Per (b,br,head); wave = one 64-row q-tile.
__global__ __launch_bounds__(256) void attn_fused(const _Float16* __restrict__ Qp,
                                                  const _Float16* __restrict__ Kb,
                                                  const _Float16* __restrict__ Vb,
                                                  _Float16* __restrict__ AOp) {
    const int b = blockIdx.y;
    const int br = blockIdx.z >> 3;
    const int head = blockIdx.z & 7;
    __shared__ _Float16 Kp[64 * 40];       // rows=kv slot (pad->64), cols=s(32), stride 40
    __shared__ _Float16 Vt[32 * 72];       // rows=s(32), cols=kv slot (pad->64), stride 72
    __shared__ _Float16 Pw[4][32 * 72];    // per-wave P half (32 q-rows x 64 kv), stride 72
    const int tid = threadIdx.x;
    const int lane = tid & 63, wave = tid >> 6;
    const size_t kvbase = (((size_t)b * 2 + br) * 8 + head) * 1568;
    {   // K stage: 64 rows x 4 chunks of 8 halfs
        int r = tid >> 2, ck = tid & 3;
        f16x8 v = {};
        if (r < 49) v = *(const f16x8*)(Kb + kvbase + r * 32 + ck * 8);
        *(f16x8*)&Kp[r * 40 + ck * 8] = v;
    }
    for (int idx = tid; idx < 64 * 32; idx += 256) {   // V stage transposed
        int w = idx >> 5, s = idx & 31;
        Vt[s * 72 + w] = (w < 49) ? Vb[kvbase + w * 32 + s] : (_Float16)0.f;
    }
    __syncthreads();
    const int mtile = blockIdx.x * 4 + wave;
    if (mtile >= 49) return;
    const int n0 = mtile * 64;
    const int lr = lane & 15, lk = lane >> 4;
    // Q' slice = head*2+br ; AO' slice = br*8+head (each tensor's natural order)
    const size_t qsl = ((size_t)b * 16 + head * 2 + br) * SLICE + (size_t)n0 * 32;
    const size_t osl = ((size_t)b * 16 + br * 8 + head) * SLICE + (size_t)n0 * 32;

    f16x8 qf[4], kf[4];
#pragma unroll
    for (int mi = 0; mi < 4; ++mi)
        qf[mi] = *(const f16x8*)(Qp + qsl + (size_t)(mi * 16 + lr) * 32 + lk * 8);
#pragma unroll
    for (int ni = 0; ni < 4; ++ni)
        kf[ni] = *(const f16x8*)&Kp[(ni * 16 + lr) * 40 + lk * 8];
    f32x4 sacc[4][4] = {};
#pragma unroll
    for (int mi = 0; mi < 4; ++mi)
#pragma unroll
        for (int ni = 0; ni < 4; ++ni)
            sacc[mi][ni] = __builtin_amdgcn_mfma_f32_16x16x32_f16(qf[mi], kf[ni], sacc[mi][ni], 0, 0, 0);

    float den[4][4];
#pragma unroll
    for (int mi = 0; mi < 4; ++mi)
#pragma unroll
        for (int j = 0; j < 4; ++j) den[mi][j] = 0.f;
    const float SCALE = 0.17677669529663687f;  // 32^-0.5
#pragma unroll
    for (int mi = 0; mi < 4; ++mi)
#pragma unroll
        for (int ni = 0; ni < 4; ++ni) {
            const bool valid = (ni * 16 + lr) < 49;
#pragma unroll
            for (int j = 0; j < 4; ++j) {
                float e = valid ? __expf(sacc[mi][ni][j] * SCALE) : 0.f;
                sacc[mi][ni][j] = e;
                den[mi][j] += e;
            }
        }
#pragma unroll
    for (int mi = 0; mi < 4; ++mi)
#pragma unroll
        for (int j = 0; j < 4; ++j) {
            float d = den[mi][j];
            d += __shfl_xor(d, 1);
            d += __shfl_xor(d, 2);
            d += __shfl_xor(d, 4);
            d += __shfl_xor(d, 8);
            den[mi][j] = 1.f / d;
        }
    // pack P to f16 early (frees sacc registers)
    f16x4 ph[4][4];
#pragma unroll
    for (int mi = 0; mi < 4; ++mi)
#pragma unroll
        for (int ni = 0; ni < 4; ++ni)
#pragma unroll
            for (int j = 0; j < 4; ++j)
                ph[mi][ni][j] = (_Float16)(sacc[mi][ni][j] * den[mi][j]);

    _Float16* P = Pw[wave];
#pragma unroll
    for (int h = 0; h < 2; ++h) {
        // write P half: q-rows h*32..h*32+31
#pragma unroll
        for (int mh = 0; mh < 2; ++mh) {
            const int mi = h * 2 + mh;
#pragma unroll
            for (int ni = 0; ni < 4; ++ni)
#pragma unroll
                for (int j = 0; j < 4; ++j)
                    P[(mh * 16 + lk * 4 + j) * 72 + ni * 16 + lr] = ph[mi][ni][j];
        }
        f32x4 oacc[2][2] = {};
#pragma unroll
        for (int k0 = 0; k0 < 2; ++k0) {
            f16x8 vf0 = *(const f16x8*)&Vt[lr * 72 + k0 * 32 + lk * 8];
            f16x8 vf1 = *(const f16x8*)&Vt[(16 + lr) * 72 + k0 * 32 + lk * 8];
#pragma unroll
            for (int mh = 0; mh < 2; ++mh) {
                f16x8 pf = *(const f16x8*)&P[(mh * 16 + lr) * 72 + k0 * 32 + lk * 8];
                oacc[mh][0] = __builtin_amdgcn_mfma_f32_16x16x32_f16(pf, vf0, oacc[mh][0], 0, 0, 0);
                oacc[mh][1] = __builtin_amdgcn_mfma_f32_16x16x32_f16(pf, vf1, oacc[mh][1], 0, 0, 0);
            }
        }
        // restage out half into P region (stride 40), then 2 coalesced 1KB stores
#pragma unroll
        for (int mh = 0; mh < 2; ++mh)
#pragma unroll
            for (int ci = 0; ci < 2; ++ci)
#pragma unroll
                for (int j = 0; j < 4; ++j)
                    P[(mh * 16 + lk * 4 + j) * 40 + ci * 16 + lr] = (_Float16)(oacc[mh][ci][j]);
#pragma unroll
        for (int t = 0; t < 2; ++t) {
            const int idx = t * 64 + lane;
            const int row = idx >> 2, ck = idx & 3;
            f16x8 ov = *(const f16x8*)&P[row * 40 + ck * 8];
            *(f16x8*)(AOp + osl + (size_t)(h * 32 + row) * 32 + ck * 8) = ov;
        }
    }
}

// ---------------------------------------------------------------------------
extern "C" void kernel_launch(void* const* d_in, const int* in_sizes, int n_in,
                              void* d_out, int out_size, void* d_ws, size_t ws_size,
                              hipStream_t stream) {
    const float* x       = (const float*)d_in[0];
    const float* q_w     = (const float*)d_in[3];
    const float* kv_dw_w = (const float*)d_in[4];
    const float* kv_dw_b = (const float*)d_in[5];
    const float* kv_pw_w = (const float*)d_in[6];
    const float* kv_pw_b = (const float*)d_in[7];
    const float* fc_w0   = (const float*)d_in[8];
    const float* fc_w1   = (const float*)d_in[9];
    const float* sg_w0   = (const float*)d_in[10];
    const float* sg_w1   = (const float*)d_in[11];
    const float* lw0     = (const float*)d_in[12];
    const float* lb0     = (const float*)d_in[13];
    const float* lw1     = (const float*)d_in[14];
    const float* lb1     = (const float*)d_in[15];
    const float* proj_w  = (const float*)d_in[16];
    const float* proj_b  = (const float*)d_in[17];

    char* ws = (char*)d_ws;
    const size_t SZ_BIG = (size_t)50176 * 512 * 2;
    _Float16* XH  = (_Float16*)(ws);                // x f16 -> later KVH
    _Float16* KVH = XH;
    _Float16* DW  = (_Float16*)(ws + SZ_BIG);       // dwconv out -> later AO'
    _Float16* AO  = DW;
    _Float16* QH  = (_Float16*)(ws + 2 * SZ_BIG);   // Q' head-blocked
    _Float16* WQ  = (_Float16*)(ws + 3 * SZ_BIG);
    _Float16* WPW = WQ + 262144;
    _Float16* WPJ = WPW + 262144;
    _Float16* KB  = WPJ + 262144;
    _Float16* VB  = KB + (size_t)16 * 2 * 8 * 49 * 32;
    float*    WT  = (float*)(VB + (size_t)16 * 2 * 8 * 49 * 32);  // 9x512 f32

    cast_f2h<<<dim3(12544), dim3(256), 0, stream>>>(x, XH, 25690112 / 8);
    prep<<<dim3(402), dim3(256), 0, stream>>>(q_w, kv_pw_w, proj_w, kv_dw_w, WQ, WPW, WPJ, WT);

    dwconv3x3<<<dim3(6272), dim3(256), 0, stream>>>(XH, WT, kv_dw_b, DW);

    gemm_bt<0><<<dim3(4, 392), dim3(256), 0, stream>>>(XH, WQ, nullptr, QH, nullptr, 50176, 512, 512);
    gemm_bt<1><<<dim3(4, 392), dim3(256), 0, stream>>>(DW, WPW, kv_pw_b, KVH, nullptr, 50176, 512, 512);

    kv_small<<<dim3(8, 2, 16), dim3(256), 0, stream>>>(KVH, fc_w0, fc_w1, sg_w0, sg_w1,
                                                       lw0, lb0, lw1, lb1, KB, VB);

    attn_fused<<<dim3(13, 16, 16), dim3(256), 0, stream>>>(QH, KB, VB, AO);

    gemm_bt<2><<<dim3(4, 392), dim3(256), 0, stream>>>(AO, WPJ, proj_b, nullptr, (float*)d_out,
                                                       50176, 512, 512);
}